// Round 9
// baseline (418.742 us; speedup 1.0000x reference)
//
#include <hip/hip_runtime.h>
#include <cstddef>

// HVAE tree decoder, fused single kernel. Round 9: r8's phase-split redone
// with the register cap lifted. Grid = 256 (1 block/CU), 512 thr (8 waves),
// 64 rows; wave w owns one 16-col nt-tile across four 16-row tiles (green r7).
// KEY: launch_bounds(512,1) -> VGPR cap 256 (r8's (512,2) meant 2 blocks/CU
// -> cap 128 -> the 48 live accs spilled: +12MB WRITE. Grid is 1/CU anyway.)
// Phase A: gru_a h-part (48 MFMAs, all waves; t2/rr/rz live across barrier)
//          overlaps pred (waves 0-3). Phase B: x-part + epilogue + store.
// AWH (48 regs) + h2o (32 regs, w<4) weights held loop-invariant in registers.
// Skip-max softmax (|logits| <~ 10 << 88, exp can't overflow); logits stored
// directly to global in fragment layout (v0+v1 of a row = one full 128B line)
// -> spred staging + dump step removed; leaves lose their empty trailing
// barrier. No inline asm (cvt_pk NaN'd r1/r2); scalar f2bf; rcp activations;
// biases pre-summed in LDS (green r3-r8); r8's gate-order numerics (green).
// SH/PSLD must be multiples of 8 shorts (16 B): frag loads are ds_read_b128.

#define BB   16384
#define HH   128
#define OO   32
#define ROWS 64

typedef __attribute__((ext_vector_type(8))) short bf8;
typedef __attribute__((ext_vector_type(4))) float f4;

#define MFMA(a, b, c) __builtin_amdgcn_mfma_f32_16x16x32_bf16(a, b, c, 0, 0, 0)

// packed-weight offsets in ws (shorts)
#define PW_Z2H 0         // [64x128]  -> 8192
#define PW_AWI 8192      // [96x128]  -> 12288
#define PW_AWH 20480     // [384x128] -> 49152
#define PW_FWI 69632     // [96x128]  -> 12288
#define PW_FWH 81920     // [384x128] -> 49152
#define PW_UA  131072    // [128x128] -> 16384
#define PW_UF  147456    // [128x128] -> 16384
#define PW_H2O 163840    // [128x32]  -> 4096
#define PW_END 167936

#define SH   136   // LDS h row stride (shorts): 272B rows (16B-aligned)
#define PSLD 40    // LDS probs row stride (shorts): 80B rows (16B-aligned)

// bias LDS layout (floats)
#define BA_RZ  0      // abi[0..255]+abh[0..255] (r at +0, z at +128)
#define BA_BH2 256    // abh gate2
#define BA_BI2 384    // abi gate2
#define BF_RZ  512
#define BF_BH2 768
#define BF_BI2 896
#define BU     1024   // uab+ufb
#define BZ2H   1152
#define BH2O   1280   // 32
#define BIAS_N 1312

__device__ __forceinline__ short f2bf(float f) {
  union { float f; unsigned u; } v; v.f = f;
  unsigned r = v.u + 0x7fff + ((v.u >> 16) & 1);   // RNE
  return (short)(r >> 16);
}
__device__ __forceinline__ float bf2f(short h) {
  union { unsigned u; float f; } v;
  v.u = ((unsigned)(unsigned short)h) << 16;
  return v.f;
}
__device__ __forceinline__ float rcp_(float x) { return __builtin_amdgcn_rcpf(x); }
__device__ __forceinline__ float sigmoidf_(float x) { return rcp_(1.0f + __expf(-x)); }
// tanh = 1 - 2/(e^{2x}+1): x>=44 -> e=inf -> rcp=0 -> 1; x<<0 -> e=0 -> -1.
__device__ __forceinline__ float tanhf_(float x) {
  const float e = __expf(2.0f * x);
  return 1.0f - 2.0f * rcp_(e + 1.0f);
}

// ---------------- repack: fp32 [K][N] -> B-frag-major bf16 -------------------
// P[((nt*KC + kc)*64 + lane)*8 + j] = W[kc*32 + (lane>>4)*8 + j][nt*16 + (lane&15)]
template <int K, int N>
__device__ __forceinline__ void repack_one(const float* __restrict__ W,
                                           short* __restrict__ P, int idx) {
  const int KC = K / 32;
  const int j = idx & 7, lane = (idx >> 3) & 63, rest = idx >> 9;
  const int kc = rest % KC, nt = rest / KC;
  const int k = kc * 32 + ((lane >> 4) << 3) + j;
  const int n = nt * 16 + (lane & 15);
  P[idx] = f2bf(W[(size_t)k * N + n]);
}

__global__ __launch_bounds__(256) void k_repack(
    const float* __restrict__ z2hw, const float* __restrict__ awi,
    const float* __restrict__ awh, const float* __restrict__ fwi,
    const float* __restrict__ fwh, const float* __restrict__ uaw,
    const float* __restrict__ ufw, const float* __restrict__ h2ow,
    short* __restrict__ ws) {
  const int t = blockIdx.x * 256 + threadIdx.x;
  if (t < PW_AWI)        repack_one<64, 128>(z2hw, ws + PW_Z2H, t - PW_Z2H);
  else if (t < PW_AWH)   repack_one<96, 128>(awi, ws + PW_AWI, t - PW_AWI);
  else if (t < PW_FWI)   repack_one<384, 128>(awh, ws + PW_AWH, t - PW_AWH);
  else if (t < PW_FWH)   repack_one<96, 128>(fwi, ws + PW_FWI, t - PW_FWI);
  else if (t < PW_UA)    repack_one<384, 128>(fwh, ws + PW_FWH, t - PW_FWH);
  else if (t < PW_UF)    repack_one<128, 128>(uaw, ws + PW_UA, t - PW_UA);
  else if (t < PW_H2O)   repack_one<128, 128>(ufw, ws + PW_UF, t - PW_UF);
  else if (t < PW_END)   repack_one<128, 32>(h2ow, ws + PW_H2O, t - PW_H2O);
}

// ---------------- slice helpers (wave w owns nt tile w; 4 row-tiles) ---------
__device__ __forceinline__ void store_slice(const f4* hv, short* dst, int lane, int w) {
  const int l15 = lane & 15, q = lane >> 4;
#pragma unroll
  for (int rt = 0; rt < 4; ++rt)
#pragma unroll
    for (int j = 0; j < 4; ++j)
      dst[(rt * 16 + q * 4 + j) * SH + w * 16 + l15] = f2bf(hv[rt][j]);
}

// GRU slice (pointer weights) — used for gru_f only (r7 green body).
__device__ __forceinline__ void gru_slice(const short* xs, const short* hsrc,
                                          const short* wiP, const short* whP,
                                          const float* brz, const float* bh2v,
                                          const float* bi2v,
                                          int lane, int w, f4* hv) {
  const int l15 = lane & 15, q = lane >> 4;
  const int col = w * 16 + l15;
  bf8 ax[4], ah[4][4];
#pragma unroll
  for (int rt = 0; rt < 4; ++rt) {
    ax[rt] = *(const bf8*)(xs + (rt * 16 + l15) * PSLD + q * 8);
#pragma unroll
    for (int c = 0; c < 4; ++c)
      ah[rt][c] = *(const bf8*)(hsrc + (rt * 16 + l15) * SH + c * 32 + q * 8);
  }
  const bf8* wi = (const bf8*)wiP;
  const bf8* wh = (const bf8*)whP;
  f4 t2[4], rg[4];
  {
    const float b = bh2v[col];
#pragma unroll
    for (int rt = 0; rt < 4; ++rt) t2[rt] = (f4){b, b, b, b};
  }
  {
    bf8 W[4];
#pragma unroll
    for (int c = 0; c < 4; ++c) W[c] = wh[(w * 12 + 8 + c) * 64 + lane];
#pragma unroll
    for (int c = 0; c < 4; ++c)
#pragma unroll
      for (int rt = 0; rt < 4; ++rt) t2[rt] = MFMA(ah[rt][c], W[c], t2[rt]);
  }
  {
    const float b = brz[col];
#pragma unroll
    for (int rt = 0; rt < 4; ++rt) rg[rt] = (f4){b, b, b, b};
  }
  {
    bf8 Wx = wi[(w * 3 + 0) * 64 + lane];
    bf8 W[4];
#pragma unroll
    for (int c = 0; c < 4; ++c) W[c] = wh[(w * 12 + 0 + c) * 64 + lane];
#pragma unroll
    for (int rt = 0; rt < 4; ++rt) rg[rt] = MFMA(ax[rt], Wx, rg[rt]);
#pragma unroll
    for (int c = 0; c < 4; ++c)
#pragma unroll
      for (int rt = 0; rt < 4; ++rt) rg[rt] = MFMA(ah[rt][c], W[c], rg[rt]);
  }
#pragma unroll
  for (int k = 0; k < 4; ++k)
#pragma unroll
    for (int j = 0; j < 4; ++j) t2[k][j] *= sigmoidf_(rg[k][j]);
  {
    const float b = bi2v[col];
#pragma unroll
    for (int k = 0; k < 4; ++k)
#pragma unroll
      for (int j = 0; j < 4; ++j) t2[k][j] += b;
  }
  {
    bf8 Wx = wi[(w * 3 + 2) * 64 + lane];
#pragma unroll
    for (int rt = 0; rt < 4; ++rt) t2[rt] = MFMA(ax[rt], Wx, t2[rt]);
  }
  {
    const float b = brz[128 + col];
#pragma unroll
    for (int rt = 0; rt < 4; ++rt) rg[rt] = (f4){b, b, b, b};
  }
  {
    bf8 Wx = wi[(w * 3 + 1) * 64 + lane];
    bf8 W[4];
#pragma unroll
    for (int c = 0; c < 4; ++c) W[c] = wh[(w * 12 + 4 + c) * 64 + lane];
#pragma unroll
    for (int rt = 0; rt < 4; ++rt) rg[rt] = MFMA(ax[rt], Wx, rg[rt]);
#pragma unroll
    for (int c = 0; c < 4; ++c)
#pragma unroll
      for (int rt = 0; rt < 4; ++rt) rg[rt] = MFMA(ah[rt][c], W[c], rg[rt]);
  }
#pragma unroll
  for (int rt = 0; rt < 4; ++rt)
#pragma unroll
    for (int j = 0; j < 4; ++j) {
      const float hc = bf2f(hsrc[(rt * 16 + q * 4 + j) * SH + col]);
      const float zz = sigmoidf_(rg[rt][j]);
      const float nn = tanhf_(t2[rt][j]);
      hv[rt][j] = nn + zz * (hc - nn);
    }
}

// preorder schedule, depth 4: type 0=root, 1=left child (gru_a), 2=right child
__device__ const unsigned char d_TYPE[31] =
    {0,1,1,1,1,2,2,1,2,2,1,1,2,2,1,2,2,1,1,1,2,2,1,2,2,1,1,2,2,1,2};
__device__ const unsigned char d_LVL[31] =
    {0,1,2,3,4,4,3,4,4,2,3,4,4,3,4,4,1,2,3,4,4,3,4,4,2,3,4,4,3,4,4};

// ---------------- the fused tree kernel -------------------------------------
__global__ __launch_bounds__(512, 1) void k_tree(
    const float* __restrict__ zf, const short* __restrict__ pw,
    const float* __restrict__ z2hb, const float* __restrict__ abi,
    const float* __restrict__ abh, const float* __restrict__ fbi,
    const float* __restrict__ fbh, const float* __restrict__ uab,
    const float* __restrict__ ufb, const float* __restrict__ h2ob,
    float* __restrict__ out) {
  __shared__ __align__(16) short hstk[5 * ROWS * SH];   // 87040 B
  __shared__ __align__(16) short hfb[ROWS * SH];        // 17408 B
  __shared__ __align__(16) short pstk[5 * ROWS * PSLD]; // 25600 B
  __shared__ float bias[BIAS_N];                        // 5248 B => 135296 B
  const int lane = threadIdx.x & 63;
  const int w = threadIdx.x >> 6;        // 8 waves, wave w owns nt tile w
  const int l15 = lane & 15, q = lane >> 4;
  const int col = w * 16 + l15;
  const int r0 = blockIdx.x * ROWS;

  // bias preload: pre-summed where the algorithm always sums them
  for (int t = threadIdx.x; t < BIAS_N; t += 512) {
    float v;
    if (t < 256)       v = abi[t] + abh[t];
    else if (t < 384)  v = abh[t];           // abh gate2
    else if (t < 512)  v = abi[t - 128];     // abi gate2
    else if (t < 768)  v = fbi[t - 512] + fbh[t - 512];
    else if (t < 896)  v = fbh[t - 512];
    else if (t < 1024) v = fbi[t - 640];
    else if (t < 1152) v = uab[t - 1024] + ufb[t - 1024];
    else if (t < 1280) v = z2hb[t - 1152];
    else               v = h2ob[t - 1280];
    bias[t] = v;
  }

  // loop-invariant weights in registers: AWH (all waves), h2o (waves 0-3)
  bf8 waR[4], waZ[4], waN[4];
  {
    const bf8* wh = (const bf8*)(pw + PW_AWH);
#pragma unroll
    for (int c = 0; c < 4; ++c) {
      waR[c] = wh[(w * 12 + 0 + c) * 64 + lane];
      waZ[c] = wh[(w * 12 + 4 + c) * 64 + lane];
      waN[c] = wh[(w * 12 + 8 + c) * 64 + lane];
    }
  }
  bf8 Wo[8];
  if (w < 4) {
    const bf8* bw = (const bf8*)(pw + PW_H2O);
#pragma unroll
    for (int f = 0; f < 8; ++f) Wo[f] = bw[f * 64 + lane];
  }
  __syncthreads();

  // root: h_in[0] = z @ z2h + b  (z read as f32, scalar f2bf in-register)
  {
    const bf8* wz = (const bf8*)(pw + PW_Z2H);
    const bf8 W0 = wz[(w * 2 + 0) * 64 + lane];
    const bf8 W1 = wz[(w * 2 + 1) * 64 + lane];
    const float b = bias[BZ2H + col];
    f4 hv[4];
#pragma unroll
    for (int rt = 0; rt < 4; ++rt) {
      const float* zr = zf + (size_t)(r0 + rt * 16 + l15) * 64 + q * 8;
      union { short s[8]; bf8 v; } A0, A1;
      {
        const f4 x0 = *(const f4*)zr, x1 = *(const f4*)(zr + 4);
#pragma unroll
        for (int j = 0; j < 4; ++j) { A0.s[j] = f2bf(x0[j]); A0.s[4 + j] = f2bf(x1[j]); }
        const f4 y0 = *(const f4*)(zr + 32), y1 = *(const f4*)(zr + 36);
#pragma unroll
        for (int j = 0; j < 4; ++j) { A1.s[j] = f2bf(y0[j]); A1.s[4 + j] = f2bf(y1[j]); }
      }
      f4 acc = (f4){b, b, b, b};
      acc = MFMA(A0.v, W0, acc);
      acc = MFMA(A1.v, W1, acc);
      hv[rt] = acc;
    }
    store_slice(hv, hstk, lane, w);
  }
  __syncthreads();

#pragma unroll 1
  for (int i = 0; i < 31; ++i) {
    const int t = d_TYPE[i];
    const int L = d_LVL[i];
    short* hcur = hstk + L * ROWS * SH;
    short* pcur = pstk + L * ROWS * PSLD;

    if (t == 2) {
      // h_f = gru_f(probs_sib, h_sib)
      f4 hf[4];
      gru_slice(pcur, hcur, pw + PW_FWI, pw + PW_FWH,
                bias + BF_RZ, bias + BF_BH2, bias + BF_BI2, lane, w, hf);
      store_slice(hf, hfb, lane, w);
      __syncthreads();
      // h2 = tanh(h_f@uf + h_par@ua + b)
      const short* hpar = hstk + (L - 1) * ROWS * SH;
      const bf8* uf = (const bf8*)(pw + PW_UF);
      const bf8* ua = (const bf8*)(pw + PW_UA);
      bf8 Wf[4], Wa[4];
#pragma unroll
      for (int c = 0; c < 4; ++c) {
        Wf[c] = uf[(w * 4 + c) * 64 + lane];
        Wa[c] = ua[(w * 4 + c) * 64 + lane];
      }
      const float b = bias[BU + col];
      f4 hv[4];
#pragma unroll
      for (int rt = 0; rt < 4; ++rt) {
        f4 acc = (f4){b, b, b, b};
#pragma unroll
        for (int c = 0; c < 4; ++c) {
          const bf8 af = *(const bf8*)(hfb + (rt * 16 + l15) * SH + c * 32 + q * 8);
          const bf8 ap = *(const bf8*)(hpar + (rt * 16 + l15) * SH + c * 32 + q * 8);
          acc = MFMA(af, Wf[c], acc);
          acc = MFMA(ap, Wa[c], acc);
        }
#pragma unroll
        for (int j = 0; j < 4; ++j) acc[j] = tanhf_(acc[j]);
        hv[rt] = acc;
      }
      store_slice(hv, hcur, lane, w);
      __syncthreads();
    }

    // ---- phase A: gru_a h-part (all waves, L<4) ∥ pred (waves 0-3) ----
    f4 t2[4], rr[4], rz[4];
    if (L < 4) {
      bf8 ah[4][4];
#pragma unroll
      for (int rt = 0; rt < 4; ++rt)
#pragma unroll
        for (int c = 0; c < 4; ++c)
          ah[rt][c] = *(const bf8*)(hcur + (rt * 16 + l15) * SH + c * 32 + q * 8);
      const float bn = bias[BA_BH2 + col];
      const float br = bias[BA_RZ + col];
      const float bz = bias[BA_RZ + 128 + col];
#pragma unroll
      for (int rt = 0; rt < 4; ++rt) {
        t2[rt] = (f4){bn, bn, bn, bn};
        rr[rt] = (f4){br, br, br, br};
        rz[rt] = (f4){bz, bz, bz, bz};
      }
#pragma unroll
      for (int c = 0; c < 4; ++c)
#pragma unroll
        for (int rt = 0; rt < 4; ++rt) t2[rt] = MFMA(ah[rt][c], waN[c], t2[rt]);
#pragma unroll
      for (int c = 0; c < 4; ++c)
#pragma unroll
        for (int rt = 0; rt < 4; ++rt) rr[rt] = MFMA(ah[rt][c], waR[c], rr[rt]);
#pragma unroll
      for (int c = 0; c < 4; ++c)
#pragma unroll
        for (int rt = 0; rt < 4; ++rt) rz[rt] = MFMA(ah[rt][c], waZ[c], rz[rt]);
    }
    if (w < 4) {
      bf8 a[4];
#pragma unroll
      for (int c = 0; c < 4; ++c)
        a[c] = *(const bf8*)(hcur + (w * 16 + l15) * SH + c * 32 + q * 8);
      const float b0 = bias[BH2O + l15];
      const float b1 = bias[BH2O + 16 + l15];
      f4 pa = (f4){b0, b0, b0, b0};
      f4 pb = (f4){b1, b1, b1, b1};
#pragma unroll
      for (int c = 0; c < 4; ++c) {
        pa = MFMA(a[c], Wo[c], pa);
        pb = MFMA(a[c], Wo[4 + c], pb);
      }
      // direct logits store, fragment layout: v0+v1 of a row = one 128B line
      float* ob = out + ((size_t)i * BB + r0 + w * 16 + q * 4) * OO + l15;
#pragma unroll
      for (int j = 0; j < 4; ++j) {
        __builtin_nontemporal_store(pa[j], ob + j * OO);
        __builtin_nontemporal_store(pb[j], ob + j * OO + 16);
      }
      // skip-max softmax (|logits| << 88: exp cannot overflow)
#pragma unroll
      for (int j = 0; j < 4; ++j) {
        const float e0 = __expf(pa[j]), e1 = __expf(pb[j]);
        float ss = e0 + e1;
#pragma unroll
        for (int s = 1; s < 16; s <<= 1) ss += __shfl_xor(ss, s);
        const float inv = rcp_(ss);
        short* pr = pcur + (w * 16 + q * 4 + j) * PSLD;
        pr[l15] = f2bf(e0 * inv);
        pr[16 + l15] = f2bf(e1 * inv);
      }
    }
    __syncthreads();

    // ---- phase B: gru_a x-part + epilogue + store (internal nodes) ----
    if (L < 4) {
      const bf8* wi = (const bf8*)(pw + PW_AWI);
      const bf8 Wxr = wi[(w * 3 + 0) * 64 + lane];
      const bf8 Wxz = wi[(w * 3 + 1) * 64 + lane];
      const bf8 Wxn = wi[(w * 3 + 2) * 64 + lane];
      bf8 ax[4];
#pragma unroll
      for (int rt = 0; rt < 4; ++rt)
        ax[rt] = *(const bf8*)(pcur + (rt * 16 + l15) * PSLD + q * 8);
#pragma unroll
      for (int rt = 0; rt < 4; ++rt) rr[rt] = MFMA(ax[rt], Wxr, rr[rt]);
      const float b2 = bias[BA_BI2 + col];
#pragma unroll
      for (int rt = 0; rt < 4; ++rt)
#pragma unroll
        for (int j = 0; j < 4; ++j)
          t2[rt][j] = t2[rt][j] * sigmoidf_(rr[rt][j]) + b2;
#pragma unroll
      for (int rt = 0; rt < 4; ++rt) t2[rt] = MFMA(ax[rt], Wxn, t2[rt]);
#pragma unroll
      for (int rt = 0; rt < 4; ++rt) rz[rt] = MFMA(ax[rt], Wxz, rz[rt]);
      f4 hv[4];
#pragma unroll
      for (int rt = 0; rt < 4; ++rt)
#pragma unroll
        for (int j = 0; j < 4; ++j) {
          const float hc = bf2f(hcur[(rt * 16 + q * 4 + j) * SH + col]);
          const float zz = sigmoidf_(rz[rt][j]);
          const float nn = tanhf_(t2[rt][j]);
          hv[rt][j] = nn + zz * (hc - nn);
        }
      store_slice(hv, hstk + (L + 1) * ROWS * SH, lane, w);
      __syncthreads();   // leaves skip this (phase B writes nothing there)
    }
  }
}

// ---------------- host ------------------------------------------------------
extern "C" void kernel_launch(void* const* d_in, const int* in_sizes, int n_in,
                              void* d_out, int out_size, void* d_ws, size_t ws_size,
                              hipStream_t stream) {
  const float* z    = (const float*)d_in[0];
  const float* z2hw = (const float*)d_in[1];
  const float* z2hb = (const float*)d_in[2];
  const float* h2ow = (const float*)d_in[3];
  const float* h2ob = (const float*)d_in[4];
  const float* awi  = (const float*)d_in[5];
  const float* abi  = (const float*)d_in[6];
  const float* awh  = (const float*)d_in[7];
  const float* abh  = (const float*)d_in[8];
  const float* fwi  = (const float*)d_in[9];
  const float* fbi  = (const float*)d_in[10];
  const float* fwh  = (const float*)d_in[11];
  const float* fbh  = (const float*)d_in[12];
  const float* uaw  = (const float*)d_in[13];
  const float* uab  = (const float*)d_in[14];
  const float* ufw  = (const float*)d_in[15];
  const float* ufb  = (const float*)d_in[16];

  float* out = (float*)d_out;
  short* ws  = (short*)d_ws;

  k_repack<<<(PW_END + 255) / 256, 256, 0, stream>>>(
      z2hw, awi, awh, fwi, fwh, uaw, ufw, h2ow, ws);

  k_tree<<<BB / ROWS, 512, 0, stream>>>(
      z, ws, z2hb, abi, abh, fbi, fbh, uab, ufb, h2ob, out);
}

// Round 10
// 258.785 us; speedup vs baseline: 1.6181x; 1.6181x over previous
//
#include <hip/hip_runtime.h>
#include <cstddef>

// HVAE tree decoder, fused single kernel. Round 10: consolidation at the
// 128-VGPR wall. Grid = 256 (1 block/CU), 512 thr (8 waves), 64 rows; wave w
// owns one 16-col nt-tile across four 16-row tiles — EXACTLY r7's gru
// structure (pointer weights, no cross-barrier register state): r7 = 204.5us,
// VGPR 128, zero spill. Empirical law from r3-r9: arch VGPRs never exceed
// ~128 with MFMA accs in the unified file; any live-state above it spills
// (r8: +48 accs, r9: +128 accs+weights -> 196MB FETCH). So: no phase-split,
// no register-resident loop-invariant weights.
// Register-neutral adds (all proven green in r9): skip-max softmax (|logit|
// <~10 << 88), direct fragment-layout nontemporal logits store (spred staging
// + dump phase removed), leaf nodes drop their empty trailing barrier.
// k_repack: 8 elems/thread, coalesced 64B reads + 16B vector writes.
// No inline asm (cvt_pk NaN'd r1/r2); scalar f2bf; rcp activations; biases
// pre-summed in LDS. SH/PSLD multiples of 8 shorts (ds_read_b128 alignment).

#define BB   16384
#define HH   128
#define OO   32
#define ROWS 64

typedef __attribute__((ext_vector_type(8))) short bf8;
typedef __attribute__((ext_vector_type(4))) float f4;

#define MFMA(a, b, c) __builtin_amdgcn_mfma_f32_16x16x32_bf16(a, b, c, 0, 0, 0)

// packed-weight offsets in ws (shorts)
#define PW_Z2H 0         // [64x128]  -> 8192
#define PW_AWI 8192      // [96x128]  -> 12288
#define PW_AWH 20480     // [384x128] -> 49152
#define PW_FWI 69632     // [96x128]  -> 12288
#define PW_FWH 81920     // [384x128] -> 49152
#define PW_UA  131072    // [128x128] -> 16384
#define PW_UF  147456    // [128x128] -> 16384
#define PW_H2O 163840    // [128x32]  -> 4096
#define PW_END 167936

#define SH   136   // LDS h row stride (shorts): 272B rows (16B-aligned)
#define PSLD 40    // LDS probs row stride (shorts): 80B rows (16B-aligned)

// bias LDS layout (floats)
#define BA_RZ  0      // abi[0..255]+abh[0..255] (r at +0, z at +128)
#define BA_BH2 256    // abh gate2
#define BA_BI2 384    // abi gate2
#define BF_RZ  512
#define BF_BH2 768
#define BF_BI2 896
#define BU     1024   // uab+ufb
#define BZ2H   1152
#define BH2O   1280   // 32
#define BIAS_N 1312

__device__ __forceinline__ short f2bf(float f) {
  union { float f; unsigned u; } v; v.f = f;
  unsigned r = v.u + 0x7fff + ((v.u >> 16) & 1);   // RNE
  return (short)(r >> 16);
}
__device__ __forceinline__ float bf2f(short h) {
  union { unsigned u; float f; } v;
  v.u = ((unsigned)(unsigned short)h) << 16;
  return v.f;
}
__device__ __forceinline__ float rcp_(float x) { return __builtin_amdgcn_rcpf(x); }
__device__ __forceinline__ float sigmoidf_(float x) { return rcp_(1.0f + __expf(-x)); }
// tanh = 1 - 2/(e^{2x}+1): x>=44 -> e=inf -> rcp=0 -> 1; x<<0 -> e=0 -> -1.
__device__ __forceinline__ float tanhf_(float x) {
  const float e = __expf(2.0f * x);
  return 1.0f - 2.0f * rcp_(e + 1.0f);
}

// ---------------- repack: fp32 [K][N] -> B-frag-major bf16 -------------------
// 8 elems per thread: thread t covers frag-slot t (16B write), j=0..7 in-lane.
// P[(t)*8 + j] = W[kc*32 + (lane>>4)*8 + j][nt*16 + (lane&15)],
//   lane = t&63, rest = t>>6, kc = rest%KC, nt = rest/KC.
// Reads: 16 consecutive f32 per (row,nt) across lanes = 64B segments.
template <int K, int N>
__device__ __forceinline__ void repack8(const float* __restrict__ W,
                                        short* __restrict__ P, int t) {
  const int KC = K / 32;
  const int lane = t & 63, rest = t >> 6;
  const int kc = rest % KC, nt = rest / KC;
  const int k0 = kc * 32 + ((lane >> 4) << 3);
  const int n = nt * 16 + (lane & 15);
  union { short s[8]; bf8 v; } u;
#pragma unroll
  for (int j = 0; j < 8; ++j) u.s[j] = f2bf(W[(size_t)(k0 + j) * N + n]);
  *(bf8*)(P + (size_t)t * 8) = u.v;
}

__global__ __launch_bounds__(256) void k_repack(
    const float* __restrict__ z2hw, const float* __restrict__ awi,
    const float* __restrict__ awh, const float* __restrict__ fwi,
    const float* __restrict__ fwh, const float* __restrict__ uaw,
    const float* __restrict__ ufw, const float* __restrict__ h2ow,
    short* __restrict__ ws) {
  const int t = blockIdx.x * 256 + threadIdx.x;
  if (t < 1024)        repack8<64, 128>(z2hw, ws + PW_Z2H, t);
  else if (t < 2560)   repack8<96, 128>(awi, ws + PW_AWI, t - 1024);
  else if (t < 8704)   repack8<384, 128>(awh, ws + PW_AWH, t - 2560);
  else if (t < 10240)  repack8<96, 128>(fwi, ws + PW_FWI, t - 8704);
  else if (t < 16384)  repack8<384, 128>(fwh, ws + PW_FWH, t - 10240);
  else if (t < 18432)  repack8<128, 128>(uaw, ws + PW_UA, t - 16384);
  else if (t < 20480)  repack8<128, 128>(ufw, ws + PW_UF, t - 18432);
  else if (t < 20992)  repack8<128, 32>(h2ow, ws + PW_H2O, t - 20480);
}

// ---------------- slice helpers (wave w owns nt tile w; 4 row-tiles) ---------
__device__ __forceinline__ void store_slice(const f4* hv, short* dst, int lane, int w) {
  const int l15 = lane & 15, q = lane >> 4;
#pragma unroll
  for (int rt = 0; rt < 4; ++rt)
#pragma unroll
    for (int j = 0; j < 4; ++j)
      dst[(rt * 16 + q * 4 + j) * SH + w * 16 + l15] = f2bf(hv[rt][j]);
}

// GRU slice (pointer weights) — r7 green body, unchanged.
__device__ __forceinline__ void gru_slice(const short* xs, const short* hsrc,
                                          const short* wiP, const short* whP,
                                          const float* brz, const float* bh2v,
                                          const float* bi2v,
                                          int lane, int w, f4* hv) {
  const int l15 = lane & 15, q = lane >> 4;
  const int col = w * 16 + l15;
  bf8 ax[4], ah[4][4];
#pragma unroll
  for (int rt = 0; rt < 4; ++rt) {
    ax[rt] = *(const bf8*)(xs + (rt * 16 + l15) * PSLD + q * 8);
#pragma unroll
    for (int c = 0; c < 4; ++c)
      ah[rt][c] = *(const bf8*)(hsrc + (rt * 16 + l15) * SH + c * 32 + q * 8);
  }
  const bf8* wi = (const bf8*)wiP;
  const bf8* wh = (const bf8*)whP;
  f4 t2[4], rg[4];
  {
    const float b = bh2v[col];
#pragma unroll
    for (int rt = 0; rt < 4; ++rt) t2[rt] = (f4){b, b, b, b};
  }
  {
    bf8 W[4];
#pragma unroll
    for (int c = 0; c < 4; ++c) W[c] = wh[(w * 12 + 8 + c) * 64 + lane];
#pragma unroll
    for (int c = 0; c < 4; ++c)
#pragma unroll
      for (int rt = 0; rt < 4; ++rt) t2[rt] = MFMA(ah[rt][c], W[c], t2[rt]);
  }
  {
    const float b = brz[col];
#pragma unroll
    for (int rt = 0; rt < 4; ++rt) rg[rt] = (f4){b, b, b, b};
  }
  {
    bf8 Wx = wi[(w * 3 + 0) * 64 + lane];
    bf8 W[4];
#pragma unroll
    for (int c = 0; c < 4; ++c) W[c] = wh[(w * 12 + 0 + c) * 64 + lane];
#pragma unroll
    for (int rt = 0; rt < 4; ++rt) rg[rt] = MFMA(ax[rt], Wx, rg[rt]);
#pragma unroll
    for (int c = 0; c < 4; ++c)
#pragma unroll
      for (int rt = 0; rt < 4; ++rt) rg[rt] = MFMA(ah[rt][c], W[c], rg[rt]);
  }
#pragma unroll
  for (int k = 0; k < 4; ++k)
#pragma unroll
    for (int j = 0; j < 4; ++j) t2[k][j] *= sigmoidf_(rg[k][j]);
  {
    const float b = bi2v[col];
#pragma unroll
    for (int k = 0; k < 4; ++k)
#pragma unroll
      for (int j = 0; j < 4; ++j) t2[k][j] += b;
  }
  {
    bf8 Wx = wi[(w * 3 + 2) * 64 + lane];
#pragma unroll
    for (int rt = 0; rt < 4; ++rt) t2[rt] = MFMA(ax[rt], Wx, t2[rt]);
  }
  {
    const float b = brz[128 + col];
#pragma unroll
    for (int rt = 0; rt < 4; ++rt) rg[rt] = (f4){b, b, b, b};
  }
  {
    bf8 Wx = wi[(w * 3 + 1) * 64 + lane];
    bf8 W[4];
#pragma unroll
    for (int c = 0; c < 4; ++c) W[c] = wh[(w * 12 + 4 + c) * 64 + lane];
#pragma unroll
    for (int rt = 0; rt < 4; ++rt) rg[rt] = MFMA(ax[rt], Wx, rg[rt]);
#pragma unroll
    for (int c = 0; c < 4; ++c)
#pragma unroll
      for (int rt = 0; rt < 4; ++rt) rg[rt] = MFMA(ah[rt][c], W[c], rg[rt]);
  }
#pragma unroll
  for (int rt = 0; rt < 4; ++rt)
#pragma unroll
    for (int j = 0; j < 4; ++j) {
      const float hc = bf2f(hsrc[(rt * 16 + q * 4 + j) * SH + col]);
      const float zz = sigmoidf_(rg[rt][j]);
      const float nn = tanhf_(t2[rt][j]);
      hv[rt][j] = nn + zz * (hc - nn);
    }
}

// preorder schedule, depth 4: type 0=root, 1=left child (gru_a), 2=right child
__device__ const unsigned char d_TYPE[31] =
    {0,1,1,1,1,2,2,1,2,2,1,1,2,2,1,2,2,1,1,1,2,2,1,2,2,1,1,2,2,1,2};
__device__ const unsigned char d_LVL[31] =
    {0,1,2,3,4,4,3,4,4,2,3,4,4,3,4,4,1,2,3,4,4,3,4,4,2,3,4,4,3,4,4};

// ---------------- the fused tree kernel -------------------------------------
__global__ __launch_bounds__(512, 2) void k_tree(
    const float* __restrict__ zf, const short* __restrict__ pw,
    const float* __restrict__ z2hb, const float* __restrict__ abi,
    const float* __restrict__ abh, const float* __restrict__ fbi,
    const float* __restrict__ fbh, const float* __restrict__ uab,
    const float* __restrict__ ufb, const float* __restrict__ h2ob,
    float* __restrict__ out) {
  __shared__ __align__(16) short hstk[5 * ROWS * SH];   // 87040 B
  __shared__ __align__(16) short hfb[ROWS * SH];        // 17408 B (type-2 only)
  __shared__ __align__(16) short pstk[5 * ROWS * PSLD]; // 25600 B
  __shared__ float bias[BIAS_N];                        // 5248 B => 135296 B
  const int lane = threadIdx.x & 63;
  const int w = threadIdx.x >> 6;        // 8 waves, wave w owns nt tile w
  const int l15 = lane & 15, q = lane >> 4;
  const int col = w * 16 + l15;
  const int r0 = blockIdx.x * ROWS;

  // bias preload: pre-summed where the algorithm always sums them
  for (int t = threadIdx.x; t < BIAS_N; t += 512) {
    float v;
    if (t < 256)       v = abi[t] + abh[t];
    else if (t < 384)  v = abh[t];           // abh gate2
    else if (t < 512)  v = abi[t - 128];     // abi gate2
    else if (t < 768)  v = fbi[t - 512] + fbh[t - 512];
    else if (t < 896)  v = fbh[t - 512];
    else if (t < 1024) v = fbi[t - 640];
    else if (t < 1152) v = uab[t - 1024] + ufb[t - 1024];
    else if (t < 1280) v = z2hb[t - 1152];
    else               v = h2ob[t - 1280];
    bias[t] = v;
  }
  __syncthreads();

  // root: h_in[0] = z @ z2h + b  (z read as f32, scalar f2bf in-register)
  {
    const bf8* wz = (const bf8*)(pw + PW_Z2H);
    const bf8 W0 = wz[(w * 2 + 0) * 64 + lane];
    const bf8 W1 = wz[(w * 2 + 1) * 64 + lane];
    const float b = bias[BZ2H + col];
    f4 hv[4];
#pragma unroll
    for (int rt = 0; rt < 4; ++rt) {
      const float* zr = zf + (size_t)(r0 + rt * 16 + l15) * 64 + q * 8;
      union { short s[8]; bf8 v; } A0, A1;
      {
        const f4 x0 = *(const f4*)zr, x1 = *(const f4*)(zr + 4);
#pragma unroll
        for (int j = 0; j < 4; ++j) { A0.s[j] = f2bf(x0[j]); A0.s[4 + j] = f2bf(x1[j]); }
        const f4 y0 = *(const f4*)(zr + 32), y1 = *(const f4*)(zr + 36);
#pragma unroll
        for (int j = 0; j < 4; ++j) { A1.s[j] = f2bf(y0[j]); A1.s[4 + j] = f2bf(y1[j]); }
      }
      f4 acc = (f4){b, b, b, b};
      acc = MFMA(A0.v, W0, acc);
      acc = MFMA(A1.v, W1, acc);
      hv[rt] = acc;
    }
    store_slice(hv, hstk, lane, w);
  }
  __syncthreads();

#pragma unroll 1
  for (int i = 0; i < 31; ++i) {
    const int t = d_TYPE[i];
    const int L = d_LVL[i];
    short* hcur = hstk + L * ROWS * SH;
    short* pcur = pstk + L * ROWS * PSLD;

    if (t == 2) {
      // h_f = gru_f(probs_sib, h_sib)
      f4 hf[4];
      gru_slice(pcur, hcur, pw + PW_FWI, pw + PW_FWH,
                bias + BF_RZ, bias + BF_BH2, bias + BF_BI2, lane, w, hf);
      store_slice(hf, hfb, lane, w);
      __syncthreads();
      // h2 = tanh(h_f@uf + h_par@ua + b)
      const short* hpar = hstk + (L - 1) * ROWS * SH;
      const bf8* uf = (const bf8*)(pw + PW_UF);
      const bf8* ua = (const bf8*)(pw + PW_UA);
      bf8 Wf[4], Wa[4];
#pragma unroll
      for (int c = 0; c < 4; ++c) {
        Wf[c] = uf[(w * 4 + c) * 64 + lane];
        Wa[c] = ua[(w * 4 + c) * 64 + lane];
      }
      const float b = bias[BU + col];
      f4 hv[4];
#pragma unroll
      for (int rt = 0; rt < 4; ++rt) {
        f4 acc = (f4){b, b, b, b};
#pragma unroll
        for (int c = 0; c < 4; ++c) {
          const bf8 af = *(const bf8*)(hfb + (rt * 16 + l15) * SH + c * 32 + q * 8);
          const bf8 ap = *(const bf8*)(hpar + (rt * 16 + l15) * SH + c * 32 + q * 8);
          acc = MFMA(af, Wf[c], acc);
          acc = MFMA(ap, Wa[c], acc);
        }
#pragma unroll
        for (int j = 0; j < 4; ++j) acc[j] = tanhf_(acc[j]);
        hv[rt] = acc;
      }
      store_slice(hv, hcur, lane, w);
      __syncthreads();
    }

    // pred + softmax: waves 0..3, one 16-row tile each. Skip-max softmax
    // (|logits| <~ 10 << 88); logits go straight to global (fragment layout:
    // pa+pb of a row = one 128B line); probs (bf16) to pstk for the GRUs.
    if (w < 4) {
      bf8 a[4];
#pragma unroll
      for (int c = 0; c < 4; ++c)
        a[c] = *(const bf8*)(hcur + (w * 16 + l15) * SH + c * 32 + q * 8);
      const bf8* bw = (const bf8*)(pw + PW_H2O);
      bf8 W[8];
#pragma unroll
      for (int f = 0; f < 8; ++f) W[f] = bw[f * 64 + lane];
      const float b0 = bias[BH2O + l15];
      const float b1 = bias[BH2O + 16 + l15];
      f4 pa = (f4){b0, b0, b0, b0};
      f4 pb = (f4){b1, b1, b1, b1};
#pragma unroll
      for (int c = 0; c < 4; ++c) {
        pa = MFMA(a[c], W[c], pa);
        pb = MFMA(a[c], W[4 + c], pb);
      }
      float* ob = out + ((size_t)i * BB + r0 + w * 16 + q * 4) * OO + l15;
#pragma unroll
      for (int j = 0; j < 4; ++j) {
        __builtin_nontemporal_store(pa[j], ob + j * OO);
        __builtin_nontemporal_store(pb[j], ob + j * OO + 16);
      }
#pragma unroll
      for (int j = 0; j < 4; ++j) {
        const float e0 = __expf(pa[j]), e1 = __expf(pb[j]);
        float ss = e0 + e1;
#pragma unroll
        for (int s = 1; s < 16; s <<= 1) ss += __shfl_xor(ss, s);
        const float inv = rcp_(ss);
        short* pr = pcur + (w * 16 + q * 4 + j) * PSLD;
        pr[l15] = f2bf(e0 * inv);
        pr[16 + l15] = f2bf(e1 * inv);
      }
    }
    __syncthreads();

    // non-leaf: h_in[L+1] = gru_a(probs, h_in[L]); leaves skip the barrier too
    if (L < 4) {
      f4 hv[4];
      gru_slice(pcur, hcur, pw + PW_AWI, pw + PW_AWH,
                bias + BA_RZ, bias + BA_BH2, bias + BA_BI2, lane, w, hv);
      store_slice(hv, hstk + (L + 1) * ROWS * SH, lane, w);
      __syncthreads();
    }
  }
}

// ---------------- host ------------------------------------------------------
extern "C" void kernel_launch(void* const* d_in, const int* in_sizes, int n_in,
                              void* d_out, int out_size, void* d_ws, size_t ws_size,
                              hipStream_t stream) {
  const float* z    = (const float*)d_in[0];
  const float* z2hw = (const float*)d_in[1];
  const float* z2hb = (const float*)d_in[2];
  const float* h2ow = (const float*)d_in[3];
  const float* h2ob = (const float*)d_in[4];
  const float* awi  = (const float*)d_in[5];
  const float* abi  = (const float*)d_in[6];
  const float* awh  = (const float*)d_in[7];
  const float* abh  = (const float*)d_in[8];
  const float* fwi  = (const float*)d_in[9];
  const float* fbi  = (const float*)d_in[10];
  const float* fwh  = (const float*)d_in[11];
  const float* fbh  = (const float*)d_in[12];
  const float* uaw  = (const float*)d_in[13];
  const float* uab  = (const float*)d_in[14];
  const float* ufw  = (const float*)d_in[15];
  const float* ufb  = (const float*)d_in[16];

  float* out = (float*)d_out;
  short* ws  = (short*)d_ws;

  k_repack<<<82, 256, 0, stream>>>(
      z2hw, awi, awh, fwi, fwh, uaw, ufw, h2ow, ws);

  k_tree<<<BB / ROWS, 512, 0, stream>>>(
      z, ws, z2hb, abi, abh, fbi, fbh, uab, ufb, h2ob, out);
}

// Round 11
// 252.363 us; speedup vs baseline: 1.6593x; 1.0254x over previous
//
#include <hip/hip_runtime.h>
#include <cstddef>

// HVAE tree decoder, fused single kernel. Round 11: k-major GRU loop.
// Grid = 256 (1 block/CU), 512 thr (8 waves), 64 rows; wave w owns one 16-col
// nt-tile across four 16-row tiles (r7/r10 structure, 181.5us, VGPR 128).
// Change vs r10: gru_slice iterates k-slices (c) outermost — per slice: load
// 4 h-frags + 3 gate weights (28 transient regs), 12 MFMAs into 48 persistent
// accs (t2/rr/rz). Per-acc k-order identical to r10 (bitwise-same); x-part
// after the k-loop (h-then-x, r9-green order). Drops ~32 regs of pinned
// ah/ax pressure -> scheduler can pipeline slice c+1 loads under slice c
// MFMAs (r10: 80 regs pinned from entry left no slack; gate groups
// serialized load->MFMA). Type-2: h_par@ua half (pre-barrier data only) runs
// between the hf store and the barrier — overlaps other waves' drain; only
// hv (16 regs) crosses the barrier.
// Register-neutral r10 features kept: skip-max softmax, direct fragment-
// layout nontemporal logits store, leaf barrier elision, 5-op tanh, fast
// repack (8 elem/thr). 128-VGPR wall law (r3-r9): no cross-barrier acc
// farms, no register-resident loop-invariant weights.
// No inline asm (cvt_pk NaN'd r1/r2); scalar f2bf; rcp activations; biases
// pre-summed in LDS. SH/PSLD multiples of 8 shorts (ds_read_b128 alignment).

#define BB   16384
#define HH   128
#define OO   32
#define ROWS 64

typedef __attribute__((ext_vector_type(8))) short bf8;
typedef __attribute__((ext_vector_type(4))) float f4;

#define MFMA(a, b, c) __builtin_amdgcn_mfma_f32_16x16x32_bf16(a, b, c, 0, 0, 0)

// packed-weight offsets in ws (shorts)
#define PW_Z2H 0         // [64x128]  -> 8192
#define PW_AWI 8192      // [96x128]  -> 12288
#define PW_AWH 20480     // [384x128] -> 49152
#define PW_FWI 69632     // [96x128]  -> 12288
#define PW_FWH 81920     // [384x128] -> 49152
#define PW_UA  131072    // [128x128] -> 16384
#define PW_UF  147456    // [128x128] -> 16384
#define PW_H2O 163840    // [128x32]  -> 4096
#define PW_END 167936

#define SH   136   // LDS h row stride (shorts): 272B rows (16B-aligned)
#define PSLD 40    // LDS probs row stride (shorts): 80B rows (16B-aligned)

// bias LDS layout (floats)
#define BA_RZ  0      // abi[0..255]+abh[0..255] (r at +0, z at +128)
#define BA_BH2 256    // abh gate2
#define BA_BI2 384    // abi gate2
#define BF_RZ  512
#define BF_BH2 768
#define BF_BI2 896
#define BU     1024   // uab+ufb
#define BZ2H   1152
#define BH2O   1280   // 32
#define BIAS_N 1312

__device__ __forceinline__ short f2bf(float f) {
  union { float f; unsigned u; } v; v.f = f;
  unsigned r = v.u + 0x7fff + ((v.u >> 16) & 1);   // RNE
  return (short)(r >> 16);
}
__device__ __forceinline__ float bf2f(short h) {
  union { unsigned u; float f; } v;
  v.u = ((unsigned)(unsigned short)h) << 16;
  return v.f;
}
__device__ __forceinline__ float rcp_(float x) { return __builtin_amdgcn_rcpf(x); }
__device__ __forceinline__ float sigmoidf_(float x) { return rcp_(1.0f + __expf(-x)); }
// tanh = 1 - 2/(e^{2x}+1): x>=44 -> e=inf -> rcp=0 -> 1; x<<0 -> e=0 -> -1.
__device__ __forceinline__ float tanhf_(float x) {
  const float e = __expf(2.0f * x);
  return 1.0f - 2.0f * rcp_(e + 1.0f);
}

// ---------------- repack: fp32 [K][N] -> B-frag-major bf16 -------------------
// 8 elems per thread: thread t covers frag-slot t (16B write), j=0..7 in-lane.
template <int K, int N>
__device__ __forceinline__ void repack8(const float* __restrict__ W,
                                        short* __restrict__ P, int t) {
  const int KC = K / 32;
  const int lane = t & 63, rest = t >> 6;
  const int kc = rest % KC, nt = rest / KC;
  const int k0 = kc * 32 + ((lane >> 4) << 3);
  const int n = nt * 16 + (lane & 15);
  union { short s[8]; bf8 v; } u;
#pragma unroll
  for (int j = 0; j < 8; ++j) u.s[j] = f2bf(W[(size_t)(k0 + j) * N + n]);
  *(bf8*)(P + (size_t)t * 8) = u.v;
}

__global__ __launch_bounds__(256) void k_repack(
    const float* __restrict__ z2hw, const float* __restrict__ awi,
    const float* __restrict__ awh, const float* __restrict__ fwi,
    const float* __restrict__ fwh, const float* __restrict__ uaw,
    const float* __restrict__ ufw, const float* __restrict__ h2ow,
    short* __restrict__ ws) {
  const int t = blockIdx.x * 256 + threadIdx.x;
  if (t < 1024)        repack8<64, 128>(z2hw, ws + PW_Z2H, t);
  else if (t < 2560)   repack8<96, 128>(awi, ws + PW_AWI, t - 1024);
  else if (t < 8704)   repack8<384, 128>(awh, ws + PW_AWH, t - 2560);
  else if (t < 10240)  repack8<96, 128>(fwi, ws + PW_FWI, t - 8704);
  else if (t < 16384)  repack8<384, 128>(fwh, ws + PW_FWH, t - 10240);
  else if (t < 18432)  repack8<128, 128>(uaw, ws + PW_UA, t - 16384);
  else if (t < 20480)  repack8<128, 128>(ufw, ws + PW_UF, t - 18432);
  else if (t < 20992)  repack8<128, 32>(h2ow, ws + PW_H2O, t - 20480);
}

// ---------------- slice helpers (wave w owns nt tile w; 4 row-tiles) ---------
__device__ __forceinline__ void store_slice(const f4* hv, short* dst, int lane, int w) {
  const int l15 = lane & 15, q = lane >> 4;
#pragma unroll
  for (int rt = 0; rt < 4; ++rt)
#pragma unroll
    for (int j = 0; j < 4; ++j)
      dst[(rt * 16 + q * 4 + j) * SH + w * 16 + l15] = f2bf(hv[rt][j]);
}

// GRU slice, k-major: per 32-wide k-slice load 4 h-frags + 3 gate weights,
// 12 MFMAs into persistent t2/rr/rz. Per-acc k-order identical to the
// gate-major form (bitwise-same accumulation); x-part after (r9-green order).
__device__ __forceinline__ void gru_slice(const short* xs, const short* hsrc,
                                          const short* wiP, const short* whP,
                                          const float* brz, const float* bh2v,
                                          const float* bi2v,
                                          int lane, int w, f4* hv) {
  const int l15 = lane & 15, q = lane >> 4;
  const int col = w * 16 + l15;
  const bf8* wi = (const bf8*)wiP;
  const bf8* wh = (const bf8*)whP;
  f4 t2[4], rr[4], rz[4];
  {
    const float bn = bh2v[col], br = brz[col], bz = brz[128 + col];
#pragma unroll
    for (int rt = 0; rt < 4; ++rt) {
      t2[rt] = (f4){bn, bn, bn, bn};
      rr[rt] = (f4){br, br, br, br};
      rz[rt] = (f4){bz, bz, bz, bz};
    }
  }
#pragma unroll
  for (int c = 0; c < 4; ++c) {
    const bf8 Wr = wh[(w * 12 + 0 + c) * 64 + lane];
    const bf8 Wz = wh[(w * 12 + 4 + c) * 64 + lane];
    const bf8 Wn = wh[(w * 12 + 8 + c) * 64 + lane];
    bf8 ah[4];
#pragma unroll
    for (int rt = 0; rt < 4; ++rt)
      ah[rt] = *(const bf8*)(hsrc + (rt * 16 + l15) * SH + c * 32 + q * 8);
#pragma unroll
    for (int rt = 0; rt < 4; ++rt) {
      rr[rt] = MFMA(ah[rt], Wr, rr[rt]);
      rz[rt] = MFMA(ah[rt], Wz, rz[rt]);
      t2[rt] = MFMA(ah[rt], Wn, t2[rt]);
    }
  }
  // x-part + epilogue
  const bf8 Wxr = wi[(w * 3 + 0) * 64 + lane];
  const bf8 Wxz = wi[(w * 3 + 1) * 64 + lane];
  const bf8 Wxn = wi[(w * 3 + 2) * 64 + lane];
  bf8 ax[4];
#pragma unroll
  for (int rt = 0; rt < 4; ++rt)
    ax[rt] = *(const bf8*)(xs + (rt * 16 + l15) * PSLD + q * 8);
#pragma unroll
  for (int rt = 0; rt < 4; ++rt) rr[rt] = MFMA(ax[rt], Wxr, rr[rt]);
  const float b2 = bi2v[col];
#pragma unroll
  for (int rt = 0; rt < 4; ++rt)
#pragma unroll
    for (int j = 0; j < 4; ++j)
      t2[rt][j] = t2[rt][j] * sigmoidf_(rr[rt][j]) + b2;  // r*(h@wh2+bh2)+bi2
#pragma unroll
  for (int rt = 0; rt < 4; ++rt) t2[rt] = MFMA(ax[rt], Wxn, t2[rt]);
#pragma unroll
  for (int rt = 0; rt < 4; ++rt) rz[rt] = MFMA(ax[rt], Wxz, rz[rt]);
  // h' = n + z*(h - n)
#pragma unroll
  for (int rt = 0; rt < 4; ++rt)
#pragma unroll
    for (int j = 0; j < 4; ++j) {
      const float hc = bf2f(hsrc[(rt * 16 + q * 4 + j) * SH + col]);
      const float zz = sigmoidf_(rz[rt][j]);
      const float nn = tanhf_(t2[rt][j]);
      hv[rt][j] = nn + zz * (hc - nn);
    }
}

// preorder schedule, depth 4: type 0=root, 1=left child (gru_a), 2=right child
__device__ const unsigned char d_TYPE[31] =
    {0,1,1,1,1,2,2,1,2,2,1,1,2,2,1,2,2,1,1,1,2,2,1,2,2,1,1,2,2,1,2};
__device__ const unsigned char d_LVL[31] =
    {0,1,2,3,4,4,3,4,4,2,3,4,4,3,4,4,1,2,3,4,4,3,4,4,2,3,4,4,3,4,4};

// ---------------- the fused tree kernel -------------------------------------
__global__ __launch_bounds__(512, 2) void k_tree(
    const float* __restrict__ zf, const short* __restrict__ pw,
    const float* __restrict__ z2hb, const float* __restrict__ abi,
    const float* __restrict__ abh, const float* __restrict__ fbi,
    const float* __restrict__ fbh, const float* __restrict__ uab,
    const float* __restrict__ ufb, const float* __restrict__ h2ob,
    float* __restrict__ out) {
  __shared__ __align__(16) short hstk[5 * ROWS * SH];   // 87040 B
  __shared__ __align__(16) short hfb[ROWS * SH];        // 17408 B (type-2 only)
  __shared__ __align__(16) short pstk[5 * ROWS * PSLD]; // 25600 B
  __shared__ float bias[BIAS_N];                        // 5248 B => 135296 B
  const int lane = threadIdx.x & 63;
  const int w = threadIdx.x >> 6;        // 8 waves, wave w owns nt tile w
  const int l15 = lane & 15, q = lane >> 4;
  const int col = w * 16 + l15;
  const int r0 = blockIdx.x * ROWS;

  // bias preload: pre-summed where the algorithm always sums them
  for (int t = threadIdx.x; t < BIAS_N; t += 512) {
    float v;
    if (t < 256)       v = abi[t] + abh[t];
    else if (t < 384)  v = abh[t];           // abh gate2
    else if (t < 512)  v = abi[t - 128];     // abi gate2
    else if (t < 768)  v = fbi[t - 512] + fbh[t - 512];
    else if (t < 896)  v = fbh[t - 512];
    else if (t < 1024) v = fbi[t - 640];
    else if (t < 1152) v = uab[t - 1024] + ufb[t - 1024];
    else if (t < 1280) v = z2hb[t - 1152];
    else               v = h2ob[t - 1280];
    bias[t] = v;
  }
  __syncthreads();

  // root: h_in[0] = z @ z2h + b  (z read as f32, scalar f2bf in-register)
  {
    const bf8* wz = (const bf8*)(pw + PW_Z2H);
    const bf8 W0 = wz[(w * 2 + 0) * 64 + lane];
    const bf8 W1 = wz[(w * 2 + 1) * 64 + lane];
    const float b = bias[BZ2H + col];
    f4 hv[4];
#pragma unroll
    for (int rt = 0; rt < 4; ++rt) {
      const float* zr = zf + (size_t)(r0 + rt * 16 + l15) * 64 + q * 8;
      union { short s[8]; bf8 v; } A0, A1;
      {
        const f4 x0 = *(const f4*)zr, x1 = *(const f4*)(zr + 4);
#pragma unroll
        for (int j = 0; j < 4; ++j) { A0.s[j] = f2bf(x0[j]); A0.s[4 + j] = f2bf(x1[j]); }
        const f4 y0 = *(const f4*)(zr + 32), y1 = *(const f4*)(zr + 36);
#pragma unroll
        for (int j = 0; j < 4; ++j) { A1.s[j] = f2bf(y0[j]); A1.s[4 + j] = f2bf(y1[j]); }
      }
      f4 acc = (f4){b, b, b, b};
      acc = MFMA(A0.v, W0, acc);
      acc = MFMA(A1.v, W1, acc);
      hv[rt] = acc;
    }
    store_slice(hv, hstk, lane, w);
  }
  __syncthreads();

#pragma unroll 1
  for (int i = 0; i < 31; ++i) {
    const int t = d_TYPE[i];
    const int L = d_LVL[i];
    short* hcur = hstk + L * ROWS * SH;
    short* pcur = pstk + L * ROWS * PSLD;

    if (t == 2) {
      // h_f = gru_f(probs_sib, h_sib)
      f4 hf[4];
      gru_slice(pcur, hcur, pw + PW_FWI, pw + PW_FWH,
                bias + BF_RZ, bias + BF_BH2, bias + BF_BI2, lane, w, hf);
      store_slice(hf, hfb, lane, w);
      // h2 = tanh(h_f@uf + h_par@ua + b): the ua half needs only pre-barrier
      // data — run it between the hf store and the barrier (overlaps drain).
      const short* hpar = hstk + (L - 1) * ROWS * SH;
      const bf8* ua = (const bf8*)(pw + PW_UA);
      f4 hv[4];
      {
        const float b = bias[BU + col];
#pragma unroll
        for (int rt = 0; rt < 4; ++rt) hv[rt] = (f4){b, b, b, b};
      }
#pragma unroll
      for (int c = 0; c < 4; ++c) {
        const bf8 Wa = ua[(w * 4 + c) * 64 + lane];
#pragma unroll
        for (int rt = 0; rt < 4; ++rt) {
          const bf8 ap = *(const bf8*)(hpar + (rt * 16 + l15) * SH + c * 32 + q * 8);
          hv[rt] = MFMA(ap, Wa, hv[rt]);
        }
      }
      __syncthreads();
      const bf8* uf = (const bf8*)(pw + PW_UF);
#pragma unroll
      for (int c = 0; c < 4; ++c) {
        const bf8 Wf = uf[(w * 4 + c) * 64 + lane];
#pragma unroll
        for (int rt = 0; rt < 4; ++rt) {
          const bf8 af = *(const bf8*)(hfb + (rt * 16 + l15) * SH + c * 32 + q * 8);
          hv[rt] = MFMA(af, Wf, hv[rt]);
        }
      }
#pragma unroll
      for (int rt = 0; rt < 4; ++rt)
#pragma unroll
        for (int j = 0; j < 4; ++j) hv[rt][j] = tanhf_(hv[rt][j]);
      store_slice(hv, hcur, lane, w);
      __syncthreads();
    }

    // pred + softmax: waves 0..3, one 16-row tile each. Skip-max softmax
    // (|logits| <~ 10 << 88); logits go straight to global (fragment layout:
    // pa+pb of a row = one 128B line); probs (bf16) to pstk for the GRUs.
    if (w < 4) {
      bf8 a[4];
#pragma unroll
      for (int c = 0; c < 4; ++c)
        a[c] = *(const bf8*)(hcur + (w * 16 + l15) * SH + c * 32 + q * 8);
      const bf8* bw = (const bf8*)(pw + PW_H2O);
      bf8 W[8];
#pragma unroll
      for (int f = 0; f < 8; ++f) W[f] = bw[f * 64 + lane];
      const float b0 = bias[BH2O + l15];
      const float b1 = bias[BH2O + 16 + l15];
      f4 pa = (f4){b0, b0, b0, b0};
      f4 pb = (f4){b1, b1, b1, b1};
#pragma unroll
      for (int c = 0; c < 4; ++c) {
        pa = MFMA(a[c], W[c], pa);
        pb = MFMA(a[c], W[4 + c], pb);
      }
      float* ob = out + ((size_t)i * BB + r0 + w * 16 + q * 4) * OO + l15;
#pragma unroll
      for (int j = 0; j < 4; ++j) {
        __builtin_nontemporal_store(pa[j], ob + j * OO);
        __builtin_nontemporal_store(pb[j], ob + j * OO + 16);
      }
#pragma unroll
      for (int j = 0; j < 4; ++j) {
        const float e0 = __expf(pa[j]), e1 = __expf(pb[j]);
        float ss = e0 + e1;
#pragma unroll
        for (int s = 1; s < 16; s <<= 1) ss += __shfl_xor(ss, s);
        const float inv = rcp_(ss);
        short* pr = pcur + (w * 16 + q * 4 + j) * PSLD;
        pr[l15] = f2bf(e0 * inv);
        pr[16 + l15] = f2bf(e1 * inv);
      }
    }
    __syncthreads();

    // non-leaf: h_in[L+1] = gru_a(probs, h_in[L]); leaves skip the barrier too
    if (L < 4) {
      f4 hv[4];
      gru_slice(pcur, hcur, pw + PW_AWI, pw + PW_AWH,
                bias + BA_RZ, bias + BA_BH2, bias + BA_BI2, lane, w, hv);
      store_slice(hv, hstk + (L + 1) * ROWS * SH, lane, w);
      __syncthreads();
    }
  }
}

// ---------------- host ------------------------------------------------------
extern "C" void kernel_launch(void* const* d_in, const int* in_sizes, int n_in,
                              void* d_out, int out_size, void* d_ws, size_t ws_size,
                              hipStream_t stream) {
  const float* z    = (const float*)d_in[0];
  const float* z2hw = (const float*)d_in[1];
  const float* z2hb = (const float*)d_in[2];
  const float* h2ow = (const float*)d_in[3];
  const float* h2ob = (const float*)d_in[4];
  const float* awi  = (const float*)d_in[5];
  const float* abi  = (const float*)d_in[6];
  const float* awh  = (const float*)d_in[7];
  const float* abh  = (const float*)d_in[8];
  const float* fwi  = (const float*)d_in[9];
  const float* fbi  = (const float*)d_in[10];
  const float* fwh  = (const float*)d_in[11];
  const float* fbh  = (const float*)d_in[12];
  const float* uaw  = (const float*)d_in[13];
  const float* uab  = (const float*)d_in[14];
  const float* ufw  = (const float*)d_in[15];
  const float* ufb  = (const float*)d_in[16];

  float* out = (float*)d_out;
  short* ws  = (short*)d_ws;

  k_repack<<<82, 256, 0, stream>>>(
      z2hw, awi, awh, fwi, fwh, uaw, ufw, h2ow, ws);

  k_tree<<<BB / ROWS, 512, 0, stream>>>(
      z, ws, z2hb, abi, abh, fbi, fbh, uab, ufb, h2ob, out);
}